// Round 1
// 484.699 us; speedup vs baseline: 1.0185x; 1.0185x over previous
//
#include <hip/hip_runtime.h>

typedef float floatx4 __attribute__((ext_vector_type(4)));
typedef _Float16 half_t;
typedef _Float16 halfx8 __attribute__((ext_vector_type(8)));
typedef _Float16 halfx4 __attribute__((ext_vector_type(4)));

#define S_LEN 2048
#define HDIM 3584
#define NHEADS 28
#define NKVH 4
#define GRP 7
#define DHEAD 128
#define KVDIM 512   // NKVH*DHEAD
#define KSPLIT 1792 // HDIM/2, K extent per split-K half

// Async global->LDS, 16B per lane. LDS dest is wave-uniform base + lane*16.
__device__ __forceinline__ void load_lds16(const half_t* g, half_t* l) {
    __builtin_amdgcn_global_load_lds(
        (__attribute__((address_space(1))) void*)(g),
        (__attribute__((address_space(3))) void*)(l), 16, 0, 0);
}

// ---------------------------------------------------------------------------
// fp32 -> f16 conversion for hidden + all weights, one launch.
// ---------------------------------------------------------------------------
__global__ __launch_bounds__(256) void cvt_kernel(
    const float* __restrict__ hidden, const float* __restrict__ Wq,
    const float* __restrict__ Wk, const float* __restrict__ Wv,
    const float* __restrict__ Wo,
    half_t* __restrict__ hh, half_t* __restrict__ wq, half_t* __restrict__ wk,
    half_t* __restrict__ wv, half_t* __restrict__ wo)
{
    int b = blockIdx.x;
    const float* src; half_t* dst; long off;
    if (b < 896)       { src = hidden; dst = hh; off = (long)b * 8192; }
    else if (b < 2464) { src = Wq; dst = wq; off = (long)(b - 896) * 8192; }
    else if (b < 2688) { src = Wk; dst = wk; off = (long)(b - 2464) * 8192; }
    else if (b < 2912) { src = Wv; dst = wv; off = (long)(b - 2688) * 8192; }
    else               { src = Wo; dst = wo; off = (long)(b - 2912) * 8192; }
    #pragma unroll
    for (int i = 0; i < 8; i++) {
        long e = off + i * 1024 + threadIdx.x * 4;
        floatx4 d = *(const floatx4*)&src[e];
        halfx4 h;
        h[0] = (half_t)d[0]; h[1] = (half_t)d[1];
        h[2] = (half_t)d[2]; h[3] = (half_t)d[3];
        *(halfx4*)&dst[e] = h;
    }
}

// ---------------------------------------------------------------------------
// Double-buffered f16 GEMM tile: C[m][n] = sum_k A[m][k]*B[n][k].
// 128x128 tile, BK=32, 4 waves x 4x4 MFMA 16x16x32 f16, 2-phase pipeline.
// Split-K aware: caller offsets A/B by k-offset, passes Klen and lda (full
// row stride). No bias: partials are reduced + biased in the fix-up pass.
// OUT_MODE: 0 = fp32 row-major, 1 = f16 row-major, 2 = f16 col-major (ldc=M).
// ---------------------------------------------------------------------------
template<int OUT_MODE>
__device__ __forceinline__ void gemm_f16(
    const half_t* __restrict__ A, const half_t* __restrict__ B,
    void* __restrict__ Cp,
    long bm, long bn, long ldc, long lda, int K, half_t* As, half_t* Bs)
{
    const int tid  = threadIdx.x;
    const int lane = tid & 63;
    const int wave = tid >> 6;
    const int wm = (wave >> 1) * 64;
    const int wn = (wave & 1) * 64;
    const int lrow = lane & 15;
    const int quad = lane >> 4;
    const int k0q = quad * 8;

    // staging map: chunk tid covers row tid>>2, cols (tid&3)*8 .. +8
    const int r0 = tid >> 2;
    const int c0 = (tid & 3) * 8;
    const half_t* a0 = &A[(bm + r0) * lda + c0];
    const half_t* a1 = a0 + 64 * lda;
    const half_t* b0 = &B[(bn + r0) * lda + c0];
    const half_t* b1 = b0 + 64 * lda;

    floatx4 acc[4][4] = {};

    // prologue: tile 0 -> buffer 0
    load_lds16(a0, &As[tid * 8]);
    load_lds16(a1, &As[2048 + tid * 8]);
    load_lds16(b0, &Bs[tid * 8]);
    load_lds16(b1, &Bs[2048 + tid * 8]);

    const int nk = K >> 5;
    for (int t = 0; t < nk; t++) {
        __syncthreads();   // tile t arrived; all waves done reading buf[(t+1)&1]
        if (t + 1 < nk) {
            const int kb = (t + 1) << 5;
            const int nb = ((t + 1) & 1) * 4096;
            load_lds16(a0 + kb, &As[nb + tid * 8]);
            load_lds16(a1 + kb, &As[nb + 2048 + tid * 8]);
            load_lds16(b0 + kb, &Bs[nb + tid * 8]);
            load_lds16(b1 + kb, &Bs[nb + 2048 + tid * 8]);
        }
        const half_t* cA = &As[(t & 1) * 4096];
        const half_t* cB = &Bs[(t & 1) * 4096];
        halfx8 af[4], bf[4];
        #pragma unroll
        for (int i = 0; i < 4; i++)
            af[i] = *(const halfx8*)&cA[(wm + i * 16 + lrow) * 32 + k0q];
        #pragma unroll
        for (int j = 0; j < 4; j++)
            bf[j] = *(const halfx8*)&cB[(wn + j * 16 + lrow) * 32 + k0q];
        #pragma unroll
        for (int i = 0; i < 4; i++)
            #pragma unroll
            for (int j = 0; j < 4; j++)
                acc[i][j] = __builtin_amdgcn_mfma_f32_16x16x32_f16(
                    af[i], bf[j], acc[i][j], 0, 0, 0);
    }

    // Epilogue: C/D layout col=lane&15, row=quad*4+reg
    #pragma unroll
    for (int j = 0; j < 4; j++) {
        long col = bn + wn + j * 16 + lrow;
        #pragma unroll
        for (int i = 0; i < 4; i++) {
            long rbase = bm + wm + i * 16 + quad * 4;
            if constexpr (OUT_MODE == 2) {
                halfx4 h;
                #pragma unroll
                for (int r = 0; r < 4; r++)
                    h[r] = (half_t)acc[i][j][r];
                *(halfx4*)&((half_t*)Cp)[col * ldc + rbase] = h;
            } else if constexpr (OUT_MODE == 1) {
                #pragma unroll
                for (int r = 0; r < 4; r++)
                    ((half_t*)Cp)[(rbase + r) * ldc + col] = (half_t)acc[i][j][r];
            } else {
                #pragma unroll
                for (int r = 0; r < 4; r++)
                    ((float*)Cp)[(rbase + r) * ldc + col] = acc[i][j][r];
            }
        }
    }
}

// Fused QKV projection, split-K=2: grid (16, 36, 2); x = row-tile,
// y = col-tile (y<28 -> Q, <32 -> K, else V^T), z = K-half.
// Writes f16 partials; reduction + bias + rope in postqkv_kernel.
__global__ __launch_bounds__(256) void qkv_kernel(
    const half_t* __restrict__ hh,
    const half_t* __restrict__ wq, const half_t* __restrict__ wk,
    const half_t* __restrict__ wv,
    half_t* __restrict__ Pq, half_t* __restrict__ Pk, half_t* __restrict__ Pv)
{
    __shared__ half_t As[2 * 128 * 32];
    __shared__ half_t Bs[2 * 128 * 32];
    int by = blockIdx.y;
    int z  = blockIdx.z;
    long koff = (long)z * KSPLIT;
    long bm = (long)blockIdx.x * 128;
    const half_t* Az = hh + koff;
    if (by < 28) {
        gemm_f16<1>(Az, wq + koff, Pq + (size_t)z * S_LEN * HDIM,
                    bm, (long)by * 128, HDIM, HDIM, KSPLIT, As, Bs);
    } else if (by < 32) {
        gemm_f16<1>(Az, wk + koff, Pk + (size_t)z * S_LEN * KVDIM,
                    bm, (long)(by - 28) * 128, KVDIM, HDIM, KSPLIT, As, Bs);
    } else {
        gemm_f16<2>(Az, wv + koff, Pv + (size_t)z * KVDIM * S_LEN,
                    bm, (long)(by - 32) * 128, S_LEN, HDIM, KSPLIT, As, Bs);
    }
}

// Output projection, split-K=2: grid (16, 28, 2), fp32 partials.
__global__ __launch_bounds__(256) void oproj_kernel(
    const half_t* __restrict__ o, const half_t* __restrict__ wo,
    float* __restrict__ Po)
{
    __shared__ half_t As[2 * 128 * 32];
    __shared__ half_t Bs[2 * 128 * 32];
    int z = blockIdx.z;
    long koff = (long)z * KSPLIT;
    gemm_f16<0>(o + koff, wo + koff, Po + (size_t)z * S_LEN * HDIM,
                (long)blockIdx.x * 128, (long)blockIdx.y * 128,
                HDIM, HDIM, KSPLIT, As, Bs);
}

// Split-K reduction + bias + RoPE (q scaled by 1/sqrt(D)) + v-bias pass.
// Blocks: [0,3584) Q pairs, [3584,4096) K pairs, [4096,5120) V elems.
__global__ __launch_bounds__(256) void postqkv_kernel(
    const half_t* __restrict__ Pq, const half_t* __restrict__ Pk,
    const half_t* __restrict__ Pv,
    const float* __restrict__ bq, const float* __restrict__ bk,
    const float* __restrict__ bv,
    const float* __restrict__ ct, const float* __restrict__ st,
    half_t* __restrict__ q, half_t* __restrict__ k, half_t* __restrict__ vt)
{
    const float scale = 0.08838834764831845f; // 128^-0.5
    int b = blockIdx.x, t = threadIdx.x;
    if (b < 3584) {           // Q: 2048*28*16 items (4 d-pairs each)
        int item = b * 256 + t;
        int s = item / 448;                  // 28*16
        int rem = item % 448;
        int h = rem >> 4, d0 = (rem & 15) * 4;
        long c = (long)h * 128 + d0;
        const half_t* p0 = Pq + (long)s * HDIM;
        const half_t* p1 = p0 + (size_t)S_LEN * HDIM;
        halfx4 a0 = *(const halfx4*)&p0[c], b0 = *(const halfx4*)&p0[c + 64];
        halfx4 a1 = *(const halfx4*)&p1[c], b1 = *(const halfx4*)&p1[c + 64];
        floatx4 cs = *(const floatx4*)&ct[s * 128 + d0];
        floatx4 sn = *(const floatx4*)&st[s * 128 + d0];
        halfx4 o1, o2;
        #pragma unroll
        for (int i = 0; i < 4; i++) {
            float x1 = (float)a0[i] + (float)a1[i] + bq[c + i];
            float x2 = (float)b0[i] + (float)b1[i] + bq[c + 64 + i];
            o1[i] = (half_t)((x1 * cs[i] - x2 * sn[i]) * scale);
            o2[i] = (half_t)((x2 * cs[i] + x1 * sn[i]) * scale);
        }
        *(halfx4*)&q[(long)s * HDIM + c] = o1;
        *(halfx4*)&q[(long)s * HDIM + c + 64] = o2;
    } else if (b < 4096) {    // K: 2048*4*16 items
        int item = (b - 3584) * 256 + t;
        int s = item >> 6;
        int rem = item & 63;
        int h = rem >> 4, d0 = (rem & 15) * 4;
        long c = (long)h * 128 + d0;
        const half_t* p0 = Pk + (long)s * KVDIM;
        const half_t* p1 = p0 + (size_t)S_LEN * KVDIM;
        halfx4 a0 = *(const halfx4*)&p0[c], b0 = *(const halfx4*)&p0[c + 64];
        halfx4 a1 = *(const halfx4*)&p1[c], b1 = *(const halfx4*)&p1[c + 64];
        floatx4 cs = *(const floatx4*)&ct[s * 128 + d0];
        floatx4 sn = *(const floatx4*)&st[s * 128 + d0];
        halfx4 o1, o2;
        #pragma unroll
        for (int i = 0; i < 4; i++) {
            float x1 = (float)a0[i] + (float)a1[i] + bk[c + i];
            float x2 = (float)b0[i] + (float)b1[i] + bk[c + 64 + i];
            o1[i] = (half_t)(x1 * cs[i] - x2 * sn[i]);
            o2[i] = (half_t)(x2 * cs[i] + x1 * sn[i]);
        }
        *(halfx4*)&k[(long)s * KVDIM + c] = o1;
        *(halfx4*)&k[(long)s * KVDIM + c + 64] = o2;
    } else {                  // V: 512 cols x 512 s4-groups, col-major partials
        int item = (b - 4096) * 256 + t;
        int col = item >> 9;
        int s4 = (item & 511) * 4;
        const half_t* p0 = Pv + (long)col * S_LEN + s4;
        const half_t* p1 = p0 + (size_t)KVDIM * S_LEN;
        float bvv = bv[col];
        halfx4 v0 = *(const halfx4*)p0, v1 = *(const halfx4*)p1, o;
        #pragma unroll
        for (int i = 0; i < 4; i++)
            o[i] = (half_t)((float)v0[i] + (float)v1[i] + bvv);
        *(halfx4*)&vt[(long)col * S_LEN + s4] = o;
    }
}

// Sum the two fp32 oproj partials into the final output.
__global__ __launch_bounds__(256) void oreduce_kernel(
    const float* __restrict__ Po, float* __restrict__ out)
{
    long i = ((long)blockIdx.x * 256 + threadIdx.x) * 4;
    floatx4 a = *(const floatx4*)&Po[i];
    floatx4 b = *(const floatx4*)&Po[(size_t)S_LEN * HDIM + i];
    *(floatx4*)&out[i] = a + b;
}

// Flash attention, barrier-free. Block = (64 q rows, 1 head), 4 independent
// waves x 16 rows. 64-key chunks; K and V^T fragments loaded directly from
// global (L2-resident); only the per-wave P C->A roundtrip uses LDS.
__global__ __launch_bounds__(256) void attn_kernel(
    const half_t* __restrict__ q, const half_t* __restrict__ k,
    const half_t* __restrict__ vt, const int* __restrict__ doc,
    half_t* __restrict__ o)
{
    constexpr int PS = 72; // 64 keys + 8 pad
    __shared__ half_t Ps[4][16 * PS];

    const int tid  = threadIdx.x;
    const int lane = tid & 63;
    const int wave = tid >> 6;
    const int head = blockIdx.y;
    const int kvh  = head / GRP;
    const int qbase = blockIdx.x * 64;
    const int lrow = lane & 15;
    const int quad = lane >> 4;
    const int k0 = quad * 8;

    const int qrow = qbase + wave * 16 + lrow;
    halfx8 qf[4];
    #pragma unroll
    for (int kk = 0; kk < 4; kk++)
        qf[kk] = *(const halfx8*)&q[(long)qrow * HDIM + head * 128 + kk * 32 + k0];

    int qdoc[4], qpos[4];
    #pragma unroll
    for (int r = 0; r < 4; r++) {
        qpos[r] = qbase + wave * 16 + quad * 4 + r;
        qdoc[r] = doc[qpos[r]];
    }

    // lower_bound(doc, doc[qbase]): skip keys before this tile's earliest doc
    int tgt = doc[qbase];
    int lo = 0, hi = qbase;
    while (lo < hi) { int mid = (lo + hi) >> 1; if (doc[mid] < tgt) lo = mid + 1; else hi = mid; }
    const int kc0 = lo & ~63;

    float m_r[4], l_r[4];
    floatx4 oacc[8] = {};
    #pragma unroll
    for (int r = 0; r < 4; r++) { m_r[r] = -INFINITY; l_r[r] = 0.0f; }

    for (int kbase = kc0; kbase <= qbase; kbase += 64) {
        floatx4 sacc[4] = {};
        #pragma unroll
        for (int s = 0; s < 4; s++) {
            const half_t* kp = &k[(long)(kbase + s * 16 + lrow) * KVDIM + kvh * 128];
            #pragma unroll
            for (int kk = 0; kk < 4; kk++) {
                halfx8 bk = *(const halfx8*)&kp[kk * 32 + k0];
                sacc[s] = __builtin_amdgcn_mfma_f32_16x16x32_f16(qf[kk], bk, sacc[s], 0, 0, 0);
            }
        }

        int kpix[4], kd[4];
        #pragma unroll
        for (int s = 0; s < 4; s++) {
            kpix[s] = kbase + s * 16 + lrow;
            kd[s] = doc[kpix[s]];
        }
        float pk[4][4];
        float alpha[4];
        #pragma unroll
        for (int r = 0; r < 4; r++) {
            float sv[4];
            float mx = -INFINITY;
            #pragma unroll
            for (int s = 0; s < 4; s++) {
                float x = sacc[s][r];
                bool valid = (kpix[s] <= qpos[r]) && (kd[s] == qdoc[r]);
                x = valid ? x : -INFINITY;
                sv[s] = x;
                mx = fmaxf(mx, x);
            }
            #pragma unroll
            for (int off = 1; off < 16; off <<= 1)
                mx = fmaxf(mx, __shfl_xor(mx, off));
            float mnew = fmaxf(m_r[r], mx);
            bool ninf = (mnew != -INFINITY);
            alpha[r] = ninf ? __expf(m_r[r] - mnew) : 1.0f;
            float sm = 0.0f;
            #pragma unroll
            for (int s = 0; s < 4; s++) {
                float p = ninf ? __expf(sv[s] - mnew) : 0.0f;
                pk[s][r] = p;
                sm += p;
            }
            #pragma unroll
            for (int off = 1; off < 16; off <<= 1)
                sm += __shfl_xor(sm, off);
            l_r[r] = l_r[r] * alpha[r] + sm;
            m_r[r] = mnew;
        }

        #pragma unroll
        for (int t = 0; t < 8; t++)
            #pragma unroll
            for (int r = 0; r < 4; r++)
                oacc[t][r] *= alpha[r];

        #pragma unroll
        for (int s = 0; s < 4; s++)
            #pragma unroll
            for (int r = 0; r < 4; r++)
                Ps[wave][(quad * 4 + r) * PS + s * 16 + lrow] = (half_t)pk[s][r];
        halfx8 pa0 = *(const halfx8*)&Ps[wave][lrow * PS + k0];
        halfx8 pa1 = *(const halfx8*)&Ps[wave][lrow * PS + 32 + k0];

        #pragma unroll
        for (int t = 0; t < 8; t++) {
            const half_t* vp = &vt[(long)(kvh * 128 + t * 16 + lrow) * S_LEN + kbase];
            halfx8 b0 = *(const halfx8*)&vp[k0];
            halfx8 b1 = *(const halfx8*)&vp[32 + k0];
            oacc[t] = __builtin_amdgcn_mfma_f32_16x16x32_f16(pa0, b0, oacc[t], 0, 0, 0);
            oacc[t] = __builtin_amdgcn_mfma_f32_16x16x32_f16(pa1, b1, oacc[t], 0, 0, 0);
        }
    }

    #pragma unroll
    for (int r = 0; r < 4; r++) {
        float inv = 1.0f / l_r[r];
        long row = qpos[r];
        #pragma unroll
        for (int t = 0; t < 8; t++)
            o[row * HDIM + head * 128 + t * 16 + lrow] = (half_t)(oacc[t][r] * inv);
    }
}

extern "C" void kernel_launch(void* const* d_in, const int* in_sizes, int n_in,
                              void* d_out, int out_size, void* d_ws, size_t ws_size,
                              hipStream_t stream) {
    const float* hidden = (const float*)d_in[0];
    const float* cosT   = (const float*)d_in[1];
    const float* sinT   = (const float*)d_in[2];
    const int*   doc    = (const int*)d_in[3];
    // d_in[4] = position_ids (unused; cos/sin precomputed)
    const float* Wq = (const float*)d_in[5];
    const float* bq = (const float*)d_in[6];
    const float* Wk = (const float*)d_in[7];
    const float* bk = (const float*)d_in[8];
    const float* Wv = (const float*)d_in[9];
    const float* bv = (const float*)d_in[10];
    const float* Wo = (const float*)d_in[11];
    float* out = (float*)d_out;

    // f16 workspace layout (halves). Total footprint ~130 MB:
    //   [hh][q][k][vt][woh][wqh][wkh][wvh][P-partials]
    // woh placed BEFORE wqh so oproj's fp32 partials Po can alias the
    // then-dead wqh..wvh + Pq..Pv region (70.8 MB >= 58.7 MB needed).
    half_t* hh  = (half_t*)d_ws;                   // dead after qkv; o reuses it
    half_t* q   = hh  + (size_t)S_LEN * HDIM;
    half_t* k   = q   + (size_t)S_LEN * HDIM;
    half_t* vt  = k   + (size_t)S_LEN * KVDIM;
    half_t* woh = vt  + (size_t)KVDIM * S_LEN;
    half_t* wqh = woh + (size_t)HDIM * HDIM;
    half_t* wkh = wqh + (size_t)HDIM * HDIM;
    half_t* wvh = wkh + (size_t)KVDIM * HDIM;
    half_t* Pq  = wvh + (size_t)KVDIM * HDIM;      // [2][S][HDIM]   f16
    half_t* Pk  = Pq  + (size_t)2 * S_LEN * HDIM;  // [2][S][KVDIM]  f16
    half_t* Pv  = Pk  + (size_t)2 * S_LEN * KVDIM; // [2][KVDIM][S]  f16 (col-major)
    half_t* o   = hh;            // alias: hh dead once qkv_kernel completes
    float*  Po  = (float*)wqh;   // alias: weights+qkv-partials dead at oproj time

    cvt_kernel<<<4480, 256, 0, stream>>>(hidden, Wq, Wk, Wv, Wo, hh, wqh, wkh, wvh, woh);
    qkv_kernel<<<dim3(16, 36, 2), 256, 0, stream>>>(hh, wqh, wkh, wvh, Pq, Pk, Pv);
    postqkv_kernel<<<5120, 256, 0, stream>>>(Pq, Pk, Pv, bq, bk, bv, cosT, sinT, q, k, vt);
    attn_kernel<<<dim3(32, NHEADS), 256, 0, stream>>>(q, k, vt, doc, o);
    oproj_kernel<<<dim3(16, 28, 2), 256, 0, stream>>>(o, woh, Po);
    oreduce_kernel<<<7168, 256, 0, stream>>>(Po, out);
}